// Round 8
// baseline (2761.564 us; speedup 1.0000x reference)
//
#include <hip/hip_runtime.h>

using half8   = __attribute__((ext_vector_type(8))) _Float16;
using f32x16  = __attribute__((ext_vector_type(16))) float;
using float4v = __attribute__((ext_vector_type(4))) float;

#define T_STEPS 256
#define BATCH   512
#define HID     2048
#define KS      128   // HID/16 k-steps
// Fragment order: ((blk32*KS + ks)*64 + lane) * 16B
// lane l: row/col = blk32*32 + (l&31), k = ks*16 + (l>>5)*8 + e

__device__ __forceinline__ f32x16 zero16() {
  f32x16 z;
#pragma unroll
  for (int r = 0; r < 16; ++r) z[r] = 0.0f;
  return z;
}

// sc0 ops: bypass L1, hit the XCD's L2 (the coherence domain for our dataflow).
__device__ __forceinline__ half8 load16_sc0(const half8* p) {
  half8 r;
  asm volatile("global_load_dwordx4 %0, %1, off sc0" : "=v"(r) : "v"(p));
  return r;
}
__device__ __forceinline__ float loadf_sc0(const float* p) {
  float r;
  asm volatile("global_load_dword %0, %1, off sc0" : "=v"(r) : "v"(p));
  return r;
}

// ---- packing kernels (proven) ----
__global__ void pack_whh_k(const float* __restrict__ whh, half8* __restrict__ bp) {
  int id   = blockIdx.x * 256 + threadIdx.x;
  int lane = id & 63;
  int ks   = (id >> 6) & 127;
  int nblk = id >> 13;
  int j = nblk * 32 + (lane & 31);
  int k = ks * 16 + (lane >> 5) * 8;
  const float4v* src = (const float4v*)(whh + (size_t)j * HID + k);
  float4v a = src[0], b = src[1];
  half8 v;
  v[0]=(_Float16)a[0]; v[1]=(_Float16)a[1]; v[2]=(_Float16)a[2]; v[3]=(_Float16)a[3];
  v[4]=(_Float16)b[0]; v[5]=(_Float16)b[1]; v[6]=(_Float16)b[2]; v[7]=(_Float16)b[3];
  bp[id] = v;
}

__global__ void pack_h_k(const float* __restrict__ hsrc, half8* __restrict__ hp) {
  int id   = blockIdx.x * 256 + threadIdx.x;
  int lane = id & 63;
  int ks   = (id >> 6) & 127;
  int bblk = id >> 13;
  int b = bblk * 32 + (lane & 31);
  int k = ks * 16 + (lane >> 5) * 8;
  const float4v* src = (const float4v*)(hsrc + (size_t)b * HID + k);
  float4v a = src[0], c = src[1];
  half8 v;
  v[0]=(_Float16)a[0]; v[1]=(_Float16)a[1]; v[2]=(_Float16)a[2]; v[3]=(_Float16)a[3];
  v[4]=(_Float16)c[0]; v[5]=(_Float16)c[1]; v[6]=(_Float16)c[2]; v[7]=(_Float16)c[3];
  hp[id] = v;
}

__global__ void bias_k(const float* __restrict__ bih, const float* __restrict__ bhh,
                       float* __restrict__ bias) {
  int i = blockIdx.x * 256 + threadIdx.x;
  if (i < HID) bias[i] = bih[i] + bhh[i];
}

// Canonicalize tf_mask + zero barrier/claim state (reset every launch).
__global__ void tf_expand_k(const int* __restrict__ tf, int* __restrict__ tfc,
                            unsigned* __restrict__ bar) {
  __shared__ int fmt;
  if (threadIdx.x == 0) {
    const unsigned* u = (const unsigned*)tf;
    int all01 = 1;
    for (int i = 0; i < 32; ++i) if (u[i] > 1u) all01 = 0;
    if (all01) {
      int odd0 = 1;
      for (int i = 1; i < 32; i += 2) if (u[i] != 0u) odd0 = 0;
      fmt = odd0 ? 2 : 1;
    } else fmt = 0;
  }
  __syncthreads();
  int i = threadIdx.x;
  int v;
  if (fmt == 2)      v = tf[2 * i];
  else if (fmt == 1) v = tf[i];
  else               v = (int)((const unsigned char*)tf)[i];
  tfc[i] = v ? 1 : 0;
  bar[i] = 0u;
}

// part/hs layout: [slab][col][rowgrp], rowgrps (4 rows as float4) XOR-swizzled:
// rowgrp' = rowgrp ^ (col & 15) -> all ds_*_b128 at the optimal 4-round bank
// pattern, zero padding.
#define PART_IDX(W_, COL_, RG_) (((W_) * 64 + (COL_)) * 16 + ((RG_) ^ ((COL_) & 15)))

#define ST_ACC(ACC, AM, AN, SLAB) do {                                     \
  int col_ = (AN) * 32 + c;                                                \
  _Pragma("unroll")                                                        \
  for (int g_ = 0; g_ < 4; ++g_) {                                         \
    int rg_ = (AM) * 8 + 2 * g_ + hi;                                      \
    float4v v_;                                                            \
    v_[0] = (ACC)[4*g_];   v_[1] = (ACC)[4*g_+1];                          \
    v_[2] = (ACC)[4*g_+2]; v_[3] = (ACC)[4*g_+3];                          \
    part4[PART_IDX(SLAB, col_, rg_)] = v_;                                 \
  } } while (0)

#define ADD_ACC(ACC, AM, AN, SLAB) do {                                    \
  int col_ = (AN) * 32 + c;                                                \
  _Pragma("unroll")                                                        \
  for (int g_ = 0; g_ < 4; ++g_) {                                         \
    int rg_ = (AM) * 8 + 2 * g_ + hi;                                      \
    int idx_ = PART_IDX(SLAB, col_, rg_);                                  \
    float4v v_ = part4[idx_];                                              \
    v_[0] += (ACC)[4*g_];   v_[1] += (ACC)[4*g_+1];                        \
    v_[2] += (ACC)[4*g_+2]; v_[3] += (ACC)[4*g_+3];                        \
    part4[idx_] = v_;                                                      \
  } } while (0)

// ---- persistent RNN kernel ----
// 256 blocks x 512 thr (8 waves), ~84KB LDS -> 1 block/CU, all co-resident
// (proven r4/r5), 32 blocks/XCD. m = XCC_ID, n = claimed rank. All cross-block
// dataflow same-XCD L2 (write-through L1 + vmcnt drain; readers sc0).
// Sync: per-XCD 32-arrival monotonic atomic barrier EVERY step (proven r5).
// bar layout: bar[x*32] arrive counter, bar[x*32+16] rank claim.
__global__ __launch_bounds__(512) void rnn_persist(
    const float* __restrict__ x0,   const float* __restrict__ tgt,
    const int*   __restrict__ tfc,  const float* __restrict__ wih,
    const float* __restrict__ wout, const float* __restrict__ bias,
    const float* __restrict__ bout, const half8* __restrict__ wp,
    half8* __restrict__ h0,         half8* __restrict__ h1,
    float* __restrict__ ypg,        float* __restrict__ out,
    unsigned* __restrict__ bar) {
  __shared__ float4v part4[4 * 64 * 16];   // 64 KB partial pre-activations
  __shared__ float4v hs4[64 * 16];         // 16 KB tanh'd h (transposed+swz)
  __shared__ float xs[64];
  __shared__ float ypart[8][64];
  __shared__ float wih_s[64], wout_s[64], bias_s[64];
  __shared__ int   tfs[T_STEPS];
  __shared__ int   mn_s[2];

  const int tid = threadIdx.x;
  const int w = tid >> 6;     // wave = k-eighth
  const int l = tid & 63;
  const int hi = l >> 5;
  const int c = l & 31;

  if (tid == 0) {
    unsigned xcc = __builtin_amdgcn_s_getreg((31 << 11) | (0 << 6) | 20) & 15u;
    unsigned x = xcc & 7u;
    unsigned r = __hip_atomic_fetch_add(&bar[x * 32 + 16], 1u, __ATOMIC_RELAXED,
                                        __HIP_MEMORY_SCOPE_AGENT);
    mn_s[0] = (int)x;
    mn_s[1] = (int)(r & 31u);
  }
  __syncthreads();
  const int m = mn_s[0];
  const int n = mn_s[1];
  const float bo = bout[0];

  if (tid < 64) {
    int j = n * 64 + tid;
    wih_s[tid]  = wih[j];
    wout_s[tid] = wout[j];
    bias_s[tid] = bias[j];
  }
  if (tid < T_STEPS) tfs[tid] = tfc[tid];

  // persistent W fragments: 32 half8 = 128 VGPR
  half8 wb0[16], wb1[16];
  {
    const half8* b0p = wp + ((size_t)(2 * n + 0) * KS + w * 16) * 64 + l;
    const half8* b1p = wp + ((size_t)(2 * n + 1) * KS + w * 16) * 64 + l;
#pragma unroll
    for (int i = 0; i < 16; ++i) { wb0[i] = b0p[i * 64]; wb1[i] = b1p[i * 64]; }
  }
  __syncthreads();

  for (int t = 0; t < T_STEPS; ++t) {
    const half8* hr = (t & 1) ? h1 : h0;
    half8*       hw = (t & 1) ? h0 : h1;

    // A-stream (sc0 -> L2) in 4 batches, MFMA vs persistent W
    f32x16 acc00 = zero16(), acc01 = zero16(), acc10 = zero16(), acc11 = zero16();
    {
      const half8* a0p = hr + ((size_t)(2 * m + 0) * KS + w * 16) * 64 + l;
      const half8* a1p = hr + ((size_t)(2 * m + 1) * KS + w * 16) * 64 + l;
#pragma unroll
      for (int kk = 0; kk < 4; ++kk) {
        half8 a0[4], a1[4];
#pragma unroll
        for (int i = 0; i < 4; ++i) {
          a0[i] = load16_sc0(a0p + (kk * 4 + i) * 64);
          a1[i] = load16_sc0(a1p + (kk * 4 + i) * 64);
        }
        asm volatile("s_waitcnt vmcnt(0)" ::: "memory");
        __builtin_amdgcn_sched_barrier(0);
        __builtin_amdgcn_s_setprio(1);
#pragma unroll
        for (int i = 0; i < 4; ++i) {
          acc00 = __builtin_amdgcn_mfma_f32_32x32x16_f16(a0[i], wb0[kk * 4 + i], acc00, 0, 0, 0);
          acc01 = __builtin_amdgcn_mfma_f32_32x32x16_f16(a0[i], wb1[kk * 4 + i], acc01, 0, 0, 0);
          acc10 = __builtin_amdgcn_mfma_f32_32x32x16_f16(a1[i], wb0[kk * 4 + i], acc10, 0, 0, 0);
          acc11 = __builtin_amdgcn_mfma_f32_32x32x16_f16(a1[i], wb1[kk * 4 + i], acc11, 0, 0, 0);
        }
        __builtin_amdgcn_s_setprio(0);
      }
    }

    // phase 1: waves 0-3 store partials (b128, swizzled)
    if (w < 4) {
      ST_ACC(acc00, 0, 0, w); ST_ACC(acc01, 0, 1, w);
      ST_ACC(acc10, 1, 0, w); ST_ACC(acc11, 1, 1, w);
    }

    // wave 0: x feedback (ypg of step t-1 is barrier-protected), overlapped
    // behind other waves' phase work. xs only read in phase 3.
    if (w == 0) {
      float x;
      if (t == 0) {
        x = x0[m * 64 + l];
      } else {
        const float* yp = ypg + ((size_t)((t - 1) & 1) * 8 + m) * 2048 + l;
        float a[32];
#pragma unroll
        for (int i = 0; i < 32; ++i) a[i] = loadf_sc0(yp + i * 64);
        asm volatile("s_waitcnt vmcnt(0)" ::: "memory");
        __builtin_amdgcn_sched_barrier(0);
        float s = 0.0f;
#pragma unroll
        for (int i = 0; i < 32; ++i) s += a[i];   // fixed order: deterministic
        float ysum = s + bo;
        if (n == 0) out[(size_t)(t - 1) * BATCH + m * 64 + l] = ysum;
        x = tfs[t - 1] ? tgt[(size_t)(t - 1) * BATCH + m * 64 + l] : ysum;
      }
      xs[l] = x;
    }
    __syncthreads();

    // phase 2: waves 4-7 accumulate in place (b128 RMW)
    if (w >= 4) {
      int s4 = w - 4;
      ADD_ACC(acc00, 0, 0, s4); ADD_ACC(acc01, 0, 1, s4);
      ADD_ACC(acc10, 1, 0, s4); ADD_ACC(acc11, 1, 1, s4);
    }
    __syncthreads();

    // phase 3: combine 4 slabs + bias + rank-1 input, tanh -> hs4 (b128)
    {
      int mb = w & 1, nb = (w >> 1) & 1, rh = w >> 2;
      int col = nb * 32 + c;
      int cx  = col & 15;
      int rg0 = mb * 8 + 4 * rh + hi;
      int rg1 = rg0 + 2;
      float4v s0 = part4[PART_IDX(0, col, rg0)];
      s0 += part4[PART_IDX(1, col, rg0)];
      s0 += part4[PART_IDX(2, col, rg0)];
      s0 += part4[PART_IDX(3, col, rg0)];
      float4v s1 = part4[PART_IDX(0, col, rg1)];
      s1 += part4[PART_IDX(1, col, rg1)];
      s1 += part4[PART_IDX(2, col, rg1)];
      s1 += part4[PART_IDX(3, col, rg1)];
      float bcol = bias_s[col], wcol = wih_s[col];
      int rb0 = mb * 32 + 16 * rh + 4 * hi;
      int rb1 = rb0 + 8;
      float4v h0v, h1v;
#pragma unroll
      for (int e = 0; e < 4; ++e) {
        h0v[e] = tanhf(s0[e] + bcol + xs[rb0 + e] * wcol);
        h1v[e] = tanhf(s1[e] + bcol + xs[rb1 + e] * wcol);
      }
      hs4[col * 16 + (rg0 ^ cx)] = h0v;
      hs4[col * 16 + (rg1 ^ cx)] = h1v;
    }
    __syncthreads();

    // repack h_t to A-fragment layout + y partials (thread: row=l, cols w*8..+8)
    {
      int row = l;
      int rg = row >> 2, re = row & 3;
      const float* hsf = (const float*)hs4;
      float hv[8];
#pragma unroll
      for (int i = 0; i < 8; ++i) {
        int col = w * 8 + i;
        hv[i] = hsf[col * 64 + ((rg ^ (col & 15)) << 2) + re];
      }
      float yp = 0.0f;
#pragma unroll
      for (int e = 0; e < 8; ++e) yp += hv[e] * wout_s[w * 8 + e];
      ypart[w][row] = yp;

      half8 f;
#pragma unroll
      for (int e = 0; e < 8; ++e) f[e] = (_Float16)hv[e];
      int bblk = 2 * m + (row >> 5);
      int ksg  = n * 4 + (w >> 1);
      int lane = (w & 1) * 32 + (row & 31);
      hw[((size_t)bblk * KS + ksg) * 64 + lane] = f;
    }
    __syncthreads();   // all waves' hw stores drained (vmcnt 0 at barrier)

    // wave 0: block's y partial -> ypg[t&1][m][n]
    if (w == 0) {
      float y = ypart[0][l] + ypart[1][l] + ypart[2][l] + ypart[3][l]
              + ypart[4][l] + ypart[5][l] + ypart[6][l] + ypart[7][l];
      ypg[(((size_t)(t & 1) * 8 + m) * 32 + n) * 64 + l] = y;
      asm volatile("s_waitcnt vmcnt(0)" ::: "memory");   // ypg in L2 pre-barrier
    }

    // per-XCD barrier: 32 arrivals, monotonic counter, EVERY step (incl. last)
    if (tid == 0) {
      __hip_atomic_fetch_add(&bar[m * 32], 1u, __ATOMIC_RELAXED,
                             __HIP_MEMORY_SCOPE_AGENT);
      unsigned tgt_cnt = 32u * (unsigned)(t + 1);
      while (__hip_atomic_load(&bar[m * 32], __ATOMIC_RELAXED,
                               __HIP_MEMORY_SCOPE_AGENT) < tgt_cnt)
        __builtin_amdgcn_s_sleep(1);
    }
    __syncthreads();
  }

  // final output row (t = T-1): barrier above makes all ypg slices visible
  if (n == 0 && tid < 64) {
    const float* yp = ypg + ((size_t)((T_STEPS - 1) & 1) * 8 + m) * 2048 + tid;
    float a[32];
#pragma unroll
    for (int i = 0; i < 32; ++i) a[i] = loadf_sc0(yp + i * 64);
    asm volatile("s_waitcnt vmcnt(0)" ::: "memory");
    __builtin_amdgcn_sched_barrier(0);
    float s = 0.0f;
#pragma unroll
    for (int i = 0; i < 32; ++i) s += a[i];
    out[(size_t)(T_STEPS - 1) * BATCH + m * 64 + tid] = s + bo;
  }
}

extern "C" void kernel_launch(void* const* d_in, const int* in_sizes, int n_in,
                              void* d_out, int out_size, void* d_ws, size_t ws_size,
                              hipStream_t stream) {
  (void)in_sizes; (void)n_in; (void)out_size; (void)ws_size;
  const float* x0   = (const float*)d_in[0];
  const float* hid  = (const float*)d_in[1];
  const float* tgt  = (const float*)d_in[2];
  const float* wih  = (const float*)d_in[3];
  const float* bih  = (const float*)d_in[4];
  const float* whh  = (const float*)d_in[5];
  const float* bhh  = (const float*)d_in[6];
  const float* wout = (const float*)d_in[7];
  const float* bout = (const float*)d_in[8];
  const int*   tf   = (const int*)d_in[9];
  float* out = (float*)d_out;

  char* ws = (char*)d_ws;
  half8*    wp   = (half8*)ws;                            // 8 MB packed W_hh fp16
  half8*    h0   = (half8*)(ws + (8u  << 20));            // 2 MB packed h (ping)
  half8*    h1   = (half8*)(ws + (10u << 20));            // 2 MB packed h (pong)
  float*    bias = (float*)(ws + (12u << 20));            // 8 KB
  int*      tfc  = (int*)  (ws + (12u << 20) + 8192);     // 1 KB
  unsigned* bar  = (unsigned*)(ws + (12u << 20) + 16384); // 1 KB barrier+claims
  float*    ypg  = (float*)(ws + (12u << 20) + 32768);    // 128 KB y partials

  pack_whh_k <<<2048, 256, 0, stream>>>(whh, wp);
  pack_h_k   <<<512,  256, 0, stream>>>(hid, h0);
  bias_k     <<<8,    256, 0, stream>>>(bih, bhh, bias);
  tf_expand_k<<<1,    256, 0, stream>>>(tf, tfc, bar);

  rnn_persist<<<256, 512, 0, stream>>>(x0, tgt, tfc, wih, wout, bias, bout,
                                       wp, h0, h1, ypg, out, bar);
}

// Round 9
// 2719.597 us; speedup vs baseline: 1.0154x; 1.0154x over previous
//
#include <hip/hip_runtime.h>

using half8   = __attribute__((ext_vector_type(8))) _Float16;
using f32x16  = __attribute__((ext_vector_type(16))) float;
using float4v = __attribute__((ext_vector_type(4))) float;

#define T_STEPS 256
#define BATCH   512
#define HID     2048
#define KS      128   // HID/16 k-steps
// Fragment order: ((blk32*KS + ks)*64 + lane) * 16B
// lane l: row/col = blk32*32 + (l&31), k = ks*16 + (l>>5)*8 + e

__device__ __forceinline__ f32x16 zero16() {
  f32x16 z;
#pragma unroll
  for (int r = 0; r < 16; ++r) z[r] = 0.0f;
  return z;
}

// sc0 ops: bypass L1, hit the XCD's L2 (the coherence domain for our dataflow).
__device__ __forceinline__ half8 load16_sc0(const half8* p) {
  half8 r;
  asm volatile("global_load_dwordx4 %0, %1, off sc0" : "=v"(r) : "v"(p));
  return r;
}
__device__ __forceinline__ float loadf_sc0(const float* p) {
  float r;
  asm volatile("global_load_dword %0, %1, off sc0" : "=v"(r) : "v"(p));
  return r;
}

// ---- packing kernels (proven) ----
__global__ void pack_whh_k(const float* __restrict__ whh, half8* __restrict__ bp) {
  int id   = blockIdx.x * 256 + threadIdx.x;
  int lane = id & 63;
  int ks   = (id >> 6) & 127;
  int nblk = id >> 13;
  int j = nblk * 32 + (lane & 31);
  int k = ks * 16 + (lane >> 5) * 8;
  const float4v* src = (const float4v*)(whh + (size_t)j * HID + k);
  float4v a = src[0], b = src[1];
  half8 v;
  v[0]=(_Float16)a[0]; v[1]=(_Float16)a[1]; v[2]=(_Float16)a[2]; v[3]=(_Float16)a[3];
  v[4]=(_Float16)b[0]; v[5]=(_Float16)b[1]; v[6]=(_Float16)b[2]; v[7]=(_Float16)b[3];
  bp[id] = v;
}

__global__ void pack_h_k(const float* __restrict__ hsrc, half8* __restrict__ hp) {
  int id   = blockIdx.x * 256 + threadIdx.x;
  int lane = id & 63;
  int ks   = (id >> 6) & 127;
  int bblk = id >> 13;
  int b = bblk * 32 + (lane & 31);
  int k = ks * 16 + (lane >> 5) * 8;
  const float4v* src = (const float4v*)(hsrc + (size_t)b * HID + k);
  float4v a = src[0], c = src[1];
  half8 v;
  v[0]=(_Float16)a[0]; v[1]=(_Float16)a[1]; v[2]=(_Float16)a[2]; v[3]=(_Float16)a[3];
  v[4]=(_Float16)c[0]; v[5]=(_Float16)c[1]; v[6]=(_Float16)c[2]; v[7]=(_Float16)c[3];
  hp[id] = v;
}

__global__ void bias_k(const float* __restrict__ bih, const float* __restrict__ bhh,
                       float* __restrict__ bias) {
  int i = blockIdx.x * 256 + threadIdx.x;
  if (i < HID) bias[i] = bih[i] + bhh[i];
}

// Canonicalize tf_mask + zero barrier/claim state (reset every launch).
__global__ void tf_expand_k(const int* __restrict__ tf, int* __restrict__ tfc,
                            unsigned* __restrict__ bar) {
  __shared__ int fmt;
  if (threadIdx.x == 0) {
    const unsigned* u = (const unsigned*)tf;
    int all01 = 1;
    for (int i = 0; i < 32; ++i) if (u[i] > 1u) all01 = 0;
    if (all01) {
      int odd0 = 1;
      for (int i = 1; i < 32; i += 2) if (u[i] != 0u) odd0 = 0;
      fmt = odd0 ? 2 : 1;
    } else fmt = 0;
  }
  __syncthreads();
  int i = threadIdx.x;
  int v;
  if (fmt == 2)      v = tf[2 * i];
  else if (fmt == 1) v = tf[i];
  else               v = (int)((const unsigned char*)tf)[i];
  tfc[i] = v ? 1 : 0;
  bar[i] = 0u;
}

// part/hs layout: [slab][col][rowgrp], rowgrps (4 rows as float4) XOR-swizzled:
// rowgrp' = rowgrp ^ (col & 15) -> all ds_*_b128 conflict-free at the b128
// minimum round count, zero padding. (Correctness validated in round 7.)
#define PART_IDX(W_, COL_, RG_) (((W_) * 64 + (COL_)) * 16 + ((RG_) ^ ((COL_) & 15)))

#define ST_ACC(ACC, AM, AN, SLAB) do {                                     \
  int col_ = (AN) * 32 + c;                                                \
  _Pragma("unroll")                                                        \
  for (int g_ = 0; g_ < 4; ++g_) {                                         \
    int rg_ = (AM) * 8 + 2 * g_ + hi;                                      \
    float4v v_;                                                            \
    v_[0] = (ACC)[4*g_];   v_[1] = (ACC)[4*g_+1];                          \
    v_[2] = (ACC)[4*g_+2]; v_[3] = (ACC)[4*g_+3];                          \
    part4[PART_IDX(SLAB, col_, rg_)] = v_;                                 \
  } } while (0)

#define ADD_ACC(ACC, AM, AN, SLAB) do {                                    \
  int col_ = (AN) * 32 + c;                                                \
  _Pragma("unroll")                                                        \
  for (int g_ = 0; g_ < 4; ++g_) {                                         \
    int rg_ = (AM) * 8 + 2 * g_ + hi;                                      \
    int idx_ = PART_IDX(SLAB, col_, rg_);                                  \
    float4v v_ = part4[idx_];                                              \
    v_[0] += (ACC)[4*g_];   v_[1] += (ACC)[4*g_+1];                        \
    v_[2] += (ACC)[4*g_+2]; v_[3] += (ACC)[4*g_+3];                        \
    part4[idx_] = v_;                                                      \
  } } while (0)

// ---- persistent RNN kernel ----
// 256 blocks x 512 thr (8 waves), ~84KB LDS -> 1 block/CU, all co-resident
// (proven r4/r5), 32 blocks/XCD. m = XCC_ID, n = claimed rank. All cross-block
// dataflow same-XCD L2 (write-through L1 + vmcnt drain; readers sc0).
// Sync: per-XCD 32-arrival monotonic atomic barrier EVERY step (incl. last).
// bar layout: bar[x*32] arrive counter, bar[x*32+16] rank claim.
// NO setprio (T5 negative on lockstep structures; suspected cause of r7
// outlier dispatches). Feedback at step top (overlaps waves 1-7's A-stream).
__global__ __launch_bounds__(512) void rnn_persist(
    const float* __restrict__ x0,   const float* __restrict__ tgt,
    const int*   __restrict__ tfc,  const float* __restrict__ wih,
    const float* __restrict__ wout, const float* __restrict__ bias,
    const float* __restrict__ bout, const half8* __restrict__ wp,
    half8* __restrict__ h0,         half8* __restrict__ h1,
    float* __restrict__ ypg,        float* __restrict__ out,
    unsigned* __restrict__ bar) {
  __shared__ float4v part4[4 * 64 * 16];   // 64 KB partial pre-activations
  __shared__ float4v hs4[64 * 16];         // 16 KB tanh'd h (transposed+swz)
  __shared__ float xs[64];
  __shared__ float ypart[8][64];
  __shared__ float wih_s[64], wout_s[64], bias_s[64];
  __shared__ int   tfs[T_STEPS];
  __shared__ int   mn_s[2];

  const int tid = threadIdx.x;
  const int w = tid >> 6;     // wave = k-eighth
  const int l = tid & 63;
  const int hi = l >> 5;
  const int c = l & 31;

  if (tid == 0) {
    unsigned xcc = __builtin_amdgcn_s_getreg((31 << 11) | (0 << 6) | 20) & 15u;
    unsigned x = xcc & 7u;
    unsigned r = __hip_atomic_fetch_add(&bar[x * 32 + 16], 1u, __ATOMIC_RELAXED,
                                        __HIP_MEMORY_SCOPE_AGENT);
    mn_s[0] = (int)x;
    mn_s[1] = (int)(r & 31u);
  }
  __syncthreads();
  const int m = mn_s[0];
  const int n = mn_s[1];
  const float bo = bout[0];

  if (tid < 64) {
    int j = n * 64 + tid;
    wih_s[tid]  = wih[j];
    wout_s[tid] = wout[j];
    bias_s[tid] = bias[j];
  }
  if (tid < T_STEPS) tfs[tid] = tfc[tid];

  // persistent W fragments: 32 half8 = 128 regs
  half8 wb0[16], wb1[16];
  {
    const half8* b0p = wp + ((size_t)(2 * n + 0) * KS + w * 16) * 64 + l;
    const half8* b1p = wp + ((size_t)(2 * n + 1) * KS + w * 16) * 64 + l;
#pragma unroll
    for (int i = 0; i < 16; ++i) { wb0[i] = b0p[i * 64]; wb1[i] = b1p[i * 64]; }
  }
  __syncthreads();

  for (int t = 0; t < T_STEPS; ++t) {
    const half8* hr = (t & 1) ? h1 : h0;
    half8*       hw = (t & 1) ? h0 : h1;

    // x feedback at step top: wave 0's L2 latency overlaps waves 1-7's A-stream.
    // ypg of step t-1 is barrier-protected. xs only read in phase 3.
    if (tid < 64) {
      float x;
      if (t == 0) {
        x = x0[m * 64 + tid];
      } else {
        const float* yp = ypg + ((size_t)((t - 1) & 1) * 8 + m) * 2048 + tid;
        float a[32];
#pragma unroll
        for (int i = 0; i < 32; ++i) a[i] = loadf_sc0(yp + i * 64);
        asm volatile("s_waitcnt vmcnt(0)" ::: "memory");
        __builtin_amdgcn_sched_barrier(0);
        float s = 0.0f;
#pragma unroll
        for (int i = 0; i < 32; ++i) s += a[i];   // fixed order: deterministic
        float ysum = s + bo;
        if (n == 0) out[(size_t)(t - 1) * BATCH + m * 64 + tid] = ysum;
        x = tfs[t - 1] ? tgt[(size_t)(t - 1) * BATCH + m * 64 + tid] : ysum;
      }
      xs[tid] = x;
    }

    // A-stream (sc0 -> L2) in 4 batches, MFMA vs persistent W
    f32x16 acc00 = zero16(), acc01 = zero16(), acc10 = zero16(), acc11 = zero16();
    {
      const half8* a0p = hr + ((size_t)(2 * m + 0) * KS + w * 16) * 64 + l;
      const half8* a1p = hr + ((size_t)(2 * m + 1) * KS + w * 16) * 64 + l;
#pragma unroll
      for (int kk = 0; kk < 4; ++kk) {
        half8 a0[4], a1[4];
#pragma unroll
        for (int i = 0; i < 4; ++i) {
          a0[i] = load16_sc0(a0p + (kk * 4 + i) * 64);
          a1[i] = load16_sc0(a1p + (kk * 4 + i) * 64);
        }
        asm volatile("s_waitcnt vmcnt(0)" ::: "memory");
        __builtin_amdgcn_sched_barrier(0);
#pragma unroll
        for (int i = 0; i < 4; ++i) {
          acc00 = __builtin_amdgcn_mfma_f32_32x32x16_f16(a0[i], wb0[kk * 4 + i], acc00, 0, 0, 0);
          acc01 = __builtin_amdgcn_mfma_f32_32x32x16_f16(a0[i], wb1[kk * 4 + i], acc01, 0, 0, 0);
          acc10 = __builtin_amdgcn_mfma_f32_32x32x16_f16(a1[i], wb0[kk * 4 + i], acc10, 0, 0, 0);
          acc11 = __builtin_amdgcn_mfma_f32_32x32x16_f16(a1[i], wb1[kk * 4 + i], acc11, 0, 0, 0);
        }
      }
    }

    // phase 1: waves 0-3 store partials (b128, swizzled)
    if (w < 4) {
      ST_ACC(acc00, 0, 0, w); ST_ACC(acc01, 0, 1, w);
      ST_ACC(acc10, 1, 0, w); ST_ACC(acc11, 1, 1, w);
    }
    __syncthreads();

    // phase 2: waves 4-7 accumulate in place (b128 RMW)
    if (w >= 4) {
      int s4 = w - 4;
      ADD_ACC(acc00, 0, 0, s4); ADD_ACC(acc01, 0, 1, s4);
      ADD_ACC(acc10, 1, 0, s4); ADD_ACC(acc11, 1, 1, s4);
    }
    __syncthreads();

    // phase 3: combine 4 slabs + bias + rank-1 input, tanh -> hs4 (b128)
    {
      int mb = w & 1, nb = (w >> 1) & 1, rh = w >> 2;
      int col = nb * 32 + c;
      int cx  = col & 15;
      int rg0 = mb * 8 + 4 * rh + hi;
      int rg1 = rg0 + 2;
      float4v s0 = part4[PART_IDX(0, col, rg0)];
      s0 += part4[PART_IDX(1, col, rg0)];
      s0 += part4[PART_IDX(2, col, rg0)];
      s0 += part4[PART_IDX(3, col, rg0)];
      float4v s1 = part4[PART_IDX(0, col, rg1)];
      s1 += part4[PART_IDX(1, col, rg1)];
      s1 += part4[PART_IDX(2, col, rg1)];
      s1 += part4[PART_IDX(3, col, rg1)];
      float bcol = bias_s[col], wcol = wih_s[col];
      int rb0 = mb * 32 + 16 * rh + 4 * hi;
      int rb1 = rb0 + 8;
      float4v h0v, h1v;
#pragma unroll
      for (int e = 0; e < 4; ++e) {
        h0v[e] = tanhf(s0[e] + bcol + xs[rb0 + e] * wcol);
        h1v[e] = tanhf(s1[e] + bcol + xs[rb1 + e] * wcol);
      }
      hs4[col * 16 + (rg0 ^ cx)] = h0v;
      hs4[col * 16 + (rg1 ^ cx)] = h1v;
    }
    __syncthreads();

    // repack h_t to A-fragment layout + y partials (thread: row=l, cols w*8..+8)
    {
      int row = l;
      int rg = row >> 2, re = row & 3;
      const float* hsf = (const float*)hs4;
      float hv[8];
#pragma unroll
      for (int i = 0; i < 8; ++i) {
        int col = w * 8 + i;
        hv[i] = hsf[col * 64 + ((rg ^ (col & 15)) << 2) + re];
      }
      float yp = 0.0f;
#pragma unroll
      for (int e = 0; e < 8; ++e) yp += hv[e] * wout_s[w * 8 + e];
      ypart[w][row] = yp;

      half8 f;
#pragma unroll
      for (int e = 0; e < 8; ++e) f[e] = (_Float16)hv[e];
      int bblk = 2 * m + (row >> 5);
      int ksg  = n * 4 + (w >> 1);
      int lane = (w & 1) * 32 + (row & 31);
      hw[((size_t)bblk * KS + ksg) * 64 + lane] = f;
    }
    __syncthreads();   // all waves' hw stores drained (vmcnt 0 at barrier)

    // wave 0: block's y partial -> ypg[t&1][m][n]
    if (w == 0) {
      float y = ypart[0][l] + ypart[1][l] + ypart[2][l] + ypart[3][l]
              + ypart[4][l] + ypart[5][l] + ypart[6][l] + ypart[7][l];
      ypg[(((size_t)(t & 1) * 8 + m) * 32 + n) * 64 + l] = y;
      asm volatile("s_waitcnt vmcnt(0)" ::: "memory");   // ypg in L2 pre-barrier
    }

    // per-XCD barrier: 32 arrivals, monotonic counter, EVERY step (incl. last)
    if (tid == 0) {
      __hip_atomic_fetch_add(&bar[m * 32], 1u, __ATOMIC_RELAXED,
                             __HIP_MEMORY_SCOPE_AGENT);
      unsigned tgt_cnt = 32u * (unsigned)(t + 1);
      while (__hip_atomic_load(&bar[m * 32], __ATOMIC_RELAXED,
                               __HIP_MEMORY_SCOPE_AGENT) < tgt_cnt)
        __builtin_amdgcn_s_sleep(1);
    }
    __syncthreads();
  }

  // final output row (t = T-1): barrier above makes all ypg slices visible
  if (n == 0 && tid < 64) {
    const float* yp = ypg + ((size_t)((T_STEPS - 1) & 1) * 8 + m) * 2048 + tid;
    float a[32];
#pragma unroll
    for (int i = 0; i < 32; ++i) a[i] = loadf_sc0(yp + i * 64);
    asm volatile("s_waitcnt vmcnt(0)" ::: "memory");
    __builtin_amdgcn_sched_barrier(0);
    float s = 0.0f;
#pragma unroll
    for (int i = 0; i < 32; ++i) s += a[i];
    out[(size_t)(T_STEPS - 1) * BATCH + m * 64 + tid] = s + bo;
  }
}

extern "C" void kernel_launch(void* const* d_in, const int* in_sizes, int n_in,
                              void* d_out, int out_size, void* d_ws, size_t ws_size,
                              hipStream_t stream) {
  (void)in_sizes; (void)n_in; (void)out_size; (void)ws_size;
  const float* x0   = (const float*)d_in[0];
  const float* hid  = (const float*)d_in[1];
  const float* tgt  = (const float*)d_in[2];
  const float* wih  = (const float*)d_in[3];
  const float* bih  = (const float*)d_in[4];
  const float* whh  = (const float*)d_in[5];
  const float* bhh  = (const float*)d_in[6];
  const float* wout = (const float*)d_in[7];
  const float* bout = (const float*)d_in[8];
  const int*   tf   = (const int*)d_in[9];
  float* out = (float*)d_out;

  char* ws = (char*)d_ws;
  half8*    wp   = (half8*)ws;                            // 8 MB packed W_hh fp16
  half8*    h0   = (half8*)(ws + (8u  << 20));            // 2 MB packed h (ping)
  half8*    h1   = (half8*)(ws + (10u << 20));            // 2 MB packed h (pong)
  float*    bias = (float*)(ws + (12u << 20));            // 8 KB
  int*      tfc  = (int*)  (ws + (12u << 20) + 8192);     // 1 KB
  unsigned* bar  = (unsigned*)(ws + (12u << 20) + 16384); // 1 KB barrier+claims
  float*    ypg  = (float*)(ws + (12u << 20) + 32768);    // 128 KB y partials

  pack_whh_k <<<2048, 256, 0, stream>>>(whh, wp);
  pack_h_k   <<<512,  256, 0, stream>>>(hid, h0);
  bias_k     <<<8,    256, 0, stream>>>(bih, bhh, bias);
  tf_expand_k<<<1,    256, 0, stream>>>(tf, tfc, bar);

  rnn_persist<<<256, 512, 0, stream>>>(x0, tgt, tfc, wih, wout, bias, bout,
                                       wp, h0, h1, ypg, out, bar);
}

// Round 11
// 2035.670 us; speedup vs baseline: 1.3566x; 1.3360x over previous
//
#include <hip/hip_runtime.h>

using half8   = __attribute__((ext_vector_type(8))) _Float16;
using f32x16  = __attribute__((ext_vector_type(16))) float;
using float4v = __attribute__((ext_vector_type(4))) float;

#define T_STEPS 256
#define BATCH   512
#define HID     2048
#define KS      128   // HID/16 k-steps
// Fragment order: ((blk32*KS + ks)*64 + lane) * 16B
// lane l: row/col = blk32*32 + (l&31), k = ks*16 + (l>>5)*8 + e

__device__ __forceinline__ f32x16 zero16() {
  f32x16 z;
#pragma unroll
  for (int r = 0; r < 16; ++r) z[r] = 0.0f;
  return z;
}

// LLC-coherent ops (sc0 sc1 = bypass L1 and L2, access the device-coherent
// Infinity Cache). Placement-independent: works whatever XCD a block runs on.
__device__ __forceinline__ half8 load16_llc(const half8* p) {
  half8 r;
  asm volatile("global_load_dwordx4 %0, %1, off sc0 sc1" : "=v"(r) : "v"(p));
  return r;
}
__device__ __forceinline__ float loadf_llc(const float* p) {
  float r;
  asm volatile("global_load_dword %0, %1, off sc0 sc1" : "=v"(r) : "v"(p));
  return r;
}
__device__ __forceinline__ void store16_llc(half8* p, half8 v) {
  asm volatile("global_store_dwordx4 %0, %1, off sc0 sc1" :: "v"(p), "v"(v) : "memory");
}
__device__ __forceinline__ void storef_llc(float* p, float v) {
  asm volatile("global_store_dword %0, %1, off sc0 sc1" :: "v"(p), "v"(v) : "memory");
}

// ---- packing kernels (proven) ----
__global__ void pack_whh_k(const float* __restrict__ whh, half8* __restrict__ bp) {
  int id   = blockIdx.x * 256 + threadIdx.x;
  int lane = id & 63;
  int ks   = (id >> 6) & 127;
  int nblk = id >> 13;
  int j = nblk * 32 + (lane & 31);
  int k = ks * 16 + (lane >> 5) * 8;
  const float4v* src = (const float4v*)(whh + (size_t)j * HID + k);
  float4v a = src[0], b = src[1];
  half8 v;
  v[0]=(_Float16)a[0]; v[1]=(_Float16)a[1]; v[2]=(_Float16)a[2]; v[3]=(_Float16)a[3];
  v[4]=(_Float16)b[0]; v[5]=(_Float16)b[1]; v[6]=(_Float16)b[2]; v[7]=(_Float16)b[3];
  bp[id] = v;
}

__global__ void pack_h_k(const float* __restrict__ hsrc, half8* __restrict__ hp) {
  int id   = blockIdx.x * 256 + threadIdx.x;
  int lane = id & 63;
  int ks   = (id >> 6) & 127;
  int bblk = id >> 13;
  int b = bblk * 32 + (lane & 31);
  int k = ks * 16 + (lane >> 5) * 8;
  const float4v* src = (const float4v*)(hsrc + (size_t)b * HID + k);
  float4v a = src[0], c = src[1];
  half8 v;
  v[0]=(_Float16)a[0]; v[1]=(_Float16)a[1]; v[2]=(_Float16)a[2]; v[3]=(_Float16)a[3];
  v[4]=(_Float16)c[0]; v[5]=(_Float16)c[1]; v[6]=(_Float16)c[2]; v[7]=(_Float16)c[3];
  hp[id] = v;
}

__global__ void bias_k(const float* __restrict__ bih, const float* __restrict__ bhh,
                       float* __restrict__ bias) {
  int i = blockIdx.x * 256 + threadIdx.x;
  if (i < HID) bias[i] = bih[i] + bhh[i];
}

// Canonicalize tf_mask + zero barrier state (reset every launch).
__global__ void tf_expand_k(const int* __restrict__ tf, int* __restrict__ tfc,
                            unsigned* __restrict__ bar) {
  __shared__ int fmt;
  if (threadIdx.x == 0) {
    const unsigned* u = (const unsigned*)tf;
    int all01 = 1;
    for (int i = 0; i < 32; ++i) if (u[i] > 1u) all01 = 0;
    if (all01) {
      int odd0 = 1;
      for (int i = 1; i < 32; i += 2) if (u[i] != 0u) odd0 = 0;
      fmt = odd0 ? 2 : 1;
    } else fmt = 0;
  }
  __syncthreads();
  int i = threadIdx.x;
  int v;
  if (fmt == 2)      v = tf[2 * i];
  else if (fmt == 1) v = tf[i];
  else               v = (int)((const unsigned char*)tf)[i];
  tfc[i] = v ? 1 : 0;
  bar[i] = 0u;
}

// ---- persistent RNN kernel ----
// 256 blocks x 512 thr (8 waves), ~90KB LDS -> 1 block/CU, co-resident.
// STATIC m = bid&7, n = bid>>3 (no XCC_ID / claims: r9's post-timing
// divergence traced to placement-trust in the XCD-local design).
// Cross-block dataflow (h fragments, ypg partials) goes through the LLC via
// sc0+sc1 ops -> coherent regardless of which XCD each block runs on.
// Sync: per-m 32-arrival monotonic atomic barrier (LLC atomics), every step.
// Epilogue: scalar LDS, conflict-free. Do NOT vectorize to b128 (r7/r8:
// register-pressure cliff -> scratch spill, WRITE_SIZE 13->172MB).
// bar layout: bar[m*32] arrive counter.
__global__ __launch_bounds__(512) void rnn_persist(
    const float* __restrict__ x0,   const float* __restrict__ tgt,
    const int*   __restrict__ tfc,  const float* __restrict__ wih,
    const float* __restrict__ wout, const float* __restrict__ bias,
    const float* __restrict__ bout, const half8* __restrict__ wp,
    half8* __restrict__ h0,         half8* __restrict__ h1,
    float* __restrict__ ypg,        float* __restrict__ out,
    unsigned* __restrict__ bar) {
  __shared__ float part[4][64][68];
  __shared__ float hs[64][68];
  __shared__ float xs[64];
  __shared__ float ypart[8][64];
  __shared__ float wih_s[64], wout_s[64], bias_s[64];
  __shared__ int   tfs[T_STEPS];

  const int bid = blockIdx.x;
  const int m = bid & 7;      // batch rows m*64..+64
  const int n = bid >> 3;     // hidden cols n*64..+64
  const int tid = threadIdx.x;
  const int w = tid >> 6;     // wave = k-eighth
  const int l = tid & 63;
  const int hi = l >> 5;
  const int c = l & 31;

  const float bo = bout[0];

  if (tid < 64) {
    int j = n * 64 + tid;
    wih_s[tid]  = wih[j];
    wout_s[tid] = wout[j];
    bias_s[tid] = bias[j];
  }
  if (tid < T_STEPS) tfs[tid] = tfc[tid];

  // persistent W fragments: 32 half8 = 128 VGPR (read-only, plain cached loads)
  half8 wb0[16], wb1[16];
  {
    const half8* b0p = wp + ((size_t)(2 * n + 0) * KS + w * 16) * 64 + l;
    const half8* b1p = wp + ((size_t)(2 * n + 1) * KS + w * 16) * 64 + l;
#pragma unroll
    for (int i = 0; i < 16; ++i) { wb0[i] = b0p[i * 64]; wb1[i] = b1p[i * 64]; }
  }
  __syncthreads();

  for (int t = 0; t < T_STEPS; ++t) {
    const half8* hr = (t & 1) ? h1 : h0;
    half8*       hw = (t & 1) ? h0 : h1;

    // x feedback at step top: wave 0's LLC latency overlaps waves 1-7's A-stream.
    // ypg of step t-1 is barrier-protected. xs only read in phase 3.
    if (tid < 64) {
      float x;
      if (t == 0) {
        x = x0[m * 64 + tid];
      } else {
        const float* yp = ypg + ((size_t)((t - 1) & 1) * 8 + m) * 2048 + tid;
        float a[32];
#pragma unroll
        for (int i = 0; i < 32; ++i) a[i] = loadf_llc(yp + i * 64);
        asm volatile("s_waitcnt vmcnt(0)" ::: "memory");
        __builtin_amdgcn_sched_barrier(0);
        float s = 0.0f;
#pragma unroll
        for (int i = 0; i < 32; ++i) s += a[i];   // fixed order: deterministic
        float ysum = s + bo;
        if (n == 0) out[(size_t)(t - 1) * BATCH + m * 64 + tid] = ysum;
        x = tfs[t - 1] ? tgt[(size_t)(t - 1) * BATCH + m * 64 + tid] : ysum;
      }
      xs[tid] = x;
    }

    // A-stream (LLC) in 4 batches, MFMA vs persistent W
    f32x16 acc00 = zero16(), acc01 = zero16(), acc10 = zero16(), acc11 = zero16();
    {
      const half8* a0p = hr + ((size_t)(2 * m + 0) * KS + w * 16) * 64 + l;
      const half8* a1p = hr + ((size_t)(2 * m + 1) * KS + w * 16) * 64 + l;
#pragma unroll
      for (int kk = 0; kk < 4; ++kk) {
        half8 a0[4], a1[4];
#pragma unroll
        for (int i = 0; i < 4; ++i) {
          a0[i] = load16_llc(a0p + (kk * 4 + i) * 64);
          a1[i] = load16_llc(a1p + (kk * 4 + i) * 64);
        }
        asm volatile("s_waitcnt vmcnt(0)" ::: "memory");
        __builtin_amdgcn_sched_barrier(0);
#pragma unroll
        for (int i = 0; i < 4; ++i) {
          acc00 = __builtin_amdgcn_mfma_f32_32x32x16_f16(a0[i], wb0[kk * 4 + i], acc00, 0, 0, 0);
          acc01 = __builtin_amdgcn_mfma_f32_32x32x16_f16(a0[i], wb1[kk * 4 + i], acc01, 0, 0, 0);
          acc10 = __builtin_amdgcn_mfma_f32_32x32x16_f16(a1[i], wb0[kk * 4 + i], acc10, 0, 0, 0);
          acc11 = __builtin_amdgcn_mfma_f32_32x32x16_f16(a1[i], wb1[kk * 4 + i], acc11, 0, 0, 0);
        }
      }
    }

    // C/D layout: col = lane&31, row = (reg&3) + 8*(reg>>2) + 4*(lane>>5)
    // phase 1: waves 0-3 store partials (scalar, conflict-free)
    if (w < 4) {
#pragma unroll
      for (int r = 0; r < 16; ++r) {
        int row0 = (r & 3) + 8 * (r >> 2) + 4 * hi;
        part[w][row0     ][c     ] = acc00[r];
        part[w][row0     ][c + 32] = acc01[r];
        part[w][row0 + 32][c     ] = acc10[r];
        part[w][row0 + 32][c + 32] = acc11[r];
      }
    }
    __syncthreads();
    // phase 2: waves 4-7 accumulate in place (same lane pattern -> no races)
    if (w >= 4) {
      int ww = w - 4;
#pragma unroll
      for (int r = 0; r < 16; ++r) {
        int row0 = (r & 3) + 8 * (r >> 2) + 4 * hi;
        part[ww][row0     ][c     ] += acc00[r];
        part[ww][row0     ][c + 32] += acc01[r];
        part[ww][row0 + 32][c     ] += acc10[r];
        part[ww][row0 + 32][c + 32] += acc11[r];
      }
    }
    __syncthreads();

    // phase 3: octant combine + bias + rank-1 input, fast tanh (r2-proven)
    {
      int mb = w & 1, nb = (w >> 1) & 1, rh = w >> 2;
#pragma unroll
      for (int r = 0; r < 8; ++r) {
        int rr = rh * 8 + r;
        int row = mb * 32 + (rr & 3) + 8 * (rr >> 2) + 4 * hi;
        int col = nb * 32 + c;
        float s = part[0][row][col] + part[1][row][col]
                + part[2][row][col] + part[3][row][col];
        s += bias_s[col] + xs[row] * wih_s[col];
        float e = __expf(2.0f * s);
        hs[row][col] = 1.0f - 2.0f / (e + 1.0f);   // tanh(s)
      }
    }
    __syncthreads();

    // repack h_t to A-fragment layout (LLC stores) + y partials
    {
      int row = tid & 63;
      int g   = tid >> 6;
      float hv[8];
      float4v v0 = *(const float4v*)&hs[row][g * 8];
      float4v v1 = *(const float4v*)&hs[row][g * 8 + 4];
      hv[0]=v0[0]; hv[1]=v0[1]; hv[2]=v0[2]; hv[3]=v0[3];
      hv[4]=v1[0]; hv[5]=v1[1]; hv[6]=v1[2]; hv[7]=v1[3];

      float yp = 0.0f;
#pragma unroll
      for (int e = 0; e < 8; ++e) yp += hv[e] * wout_s[g * 8 + e];
      ypart[g][row] = yp;

      half8 f;
#pragma unroll
      for (int e = 0; e < 8; ++e) f[e] = (_Float16)hv[e];
      int bblk = 2 * m + (row >> 5);
      int ksg  = n * 4 + (g >> 1);
      int lane = (g & 1) * 32 + (row & 31);
      store16_llc(hw + ((size_t)bblk * KS + ksg) * 64 + lane, f);
    }
    __syncthreads();   // all waves' h stores acked at LLC (vmcnt 0 at barrier)

    // wave 0: block's y partial -> ypg[t&1][m][n] (LLC)
    if (w == 0) {
      float y = ypart[0][l] + ypart[1][l] + ypart[2][l] + ypart[3][l]
              + ypart[4][l] + ypart[5][l] + ypart[6][l] + ypart[7][l];
      storef_llc(ypg + (((size_t)(t & 1) * 8 + m) * 32 + n) * 64 + l, y);
      asm volatile("s_waitcnt vmcnt(0)" ::: "memory");   // ypg at LLC pre-arrival
    }

    // per-m barrier: 32 arrivals, monotonic LLC atomic counter, every step.
    // Placement-independent: counts blocks with the same m wherever they run.
    if (tid == 0) {
      __hip_atomic_fetch_add(&bar[m * 32], 1u, __ATOMIC_RELAXED,
                             __HIP_MEMORY_SCOPE_AGENT);
      unsigned tgt_cnt = 32u * (unsigned)(t + 1);
      while (__hip_atomic_load(&bar[m * 32], __ATOMIC_RELAXED,
                               __HIP_MEMORY_SCOPE_AGENT) < tgt_cnt)
        __builtin_amdgcn_s_sleep(1);
    }
    __syncthreads();
  }

  // final output row (t = T-1): barrier above makes all ypg slices visible
  if (n == 0 && tid < 64) {
    const float* yp = ypg + ((size_t)((T_STEPS - 1) & 1) * 8 + m) * 2048 + tid;
    float a[32];
#pragma unroll
    for (int i = 0; i < 32; ++i) a[i] = loadf_llc(yp + i * 64);
    asm volatile("s_waitcnt vmcnt(0)" ::: "memory");
    __builtin_amdgcn_sched_barrier(0);
    float s = 0.0f;
#pragma unroll
    for (int i = 0; i < 32; ++i) s += a[i];
    out[(size_t)(T_STEPS - 1) * BATCH + m * 64 + tid] = s + bo;
  }
}

extern "C" void kernel_launch(void* const* d_in, const int* in_sizes, int n_in,
                              void* d_out, int out_size, void* d_ws, size_t ws_size,
                              hipStream_t stream) {
  (void)in_sizes; (void)n_in; (void)out_size; (void)ws_size;
  const float* x0   = (const float*)d_in[0];
  const float* hid  = (const float*)d_in[1];
  const float* tgt  = (const float*)d_in[2];
  const float* wih  = (const float*)d_in[3];
  const float* bih  = (const float*)d_in[4];
  const float* whh  = (const float*)d_in[5];
  const float* bhh  = (const float*)d_in[6];
  const float* wout = (const float*)d_in[7];
  const float* bout = (const float*)d_in[8];
  const int*   tf   = (const int*)d_in[9];
  float* out = (float*)d_out;

  char* ws = (char*)d_ws;
  half8*    wp   = (half8*)ws;                            // 8 MB packed W_hh fp16
  half8*    h0   = (half8*)(ws + (8u  << 20));            // 2 MB packed h (ping)
  half8*    h1   = (half8*)(ws + (10u << 20));            // 2 MB packed h (pong)
  float*    bias = (float*)(ws + (12u << 20));            // 8 KB
  int*      tfc  = (int*)  (ws + (12u << 20) + 8192);     // 1 KB
  unsigned* bar  = (unsigned*)(ws + (12u << 20) + 16384); // 1 KB barrier
  float*    ypg  = (float*)(ws + (12u << 20) + 32768);    // 128 KB y partials

  pack_whh_k <<<2048, 256, 0, stream>>>(whh, wp);
  pack_h_k   <<<512,  256, 0, stream>>>(hid, h0);
  bias_k     <<<8,    256, 0, stream>>>(bih, bhh, bias);
  tf_expand_k<<<1,    256, 0, stream>>>(tf, tfc, bar);

  rnn_persist<<<256, 512, 0, stream>>>(x0, tgt, tfc, wih, wout, bias, bout,
                                       wp, h0, h1, ypg, out, bar);
}